// Round 8
// baseline (453.160 us; speedup 1.0000x reference)
//
#include <hip/hip_runtime.h>
#include <stdint.h>

#define D_DIM 2048
#define K_DIM 64
#define T_DIM 2048
#define BT_DIM 16384   // B*T = 8*2048

typedef __attribute__((address_space(3))) uint32_t lds_u32;
typedef const __attribute__((address_space(1))) uint32_t glob_u32;

// ---------------------------------------------------------------------------
// Kernel A: softmax over k of w[d,:], stored PACKED for the gemm:
//   pC[(d>>2)*256 + k*4 + (d&3)] = softmax(w[d,:])[k]
// ---------------------------------------------------------------------------
__global__ __launch_bounds__(256) void softmax_k(const float* __restrict__ w,
                                                 float* __restrict__ pC) {
    const int lane = threadIdx.x & 63;
    const int d = blockIdx.x * 4 + (threadIdx.x >> 6);
    float v = w[d * K_DIM + lane];
    float m = v;
#pragma unroll
    for (int off = 32; off > 0; off >>= 1) m = fmaxf(m, __shfl_xor(m, off, 64));
    float e = expf(v - m);
    float s = e;
#pragma unroll
    for (int off = 32; off > 0; off >>= 1) s += __shfl_xor(s, off, 64);
    pC[(d >> 2) * 256 + lane * 4 + (d & 3)] = e / s;
}

// ---------------------------------------------------------------------------
// Kernel B: per-column min/max of w -> nT[k,d] = (w[d,k]-mn)/(mx-mn).
// ---------------------------------------------------------------------------
__global__ __launch_bounds__(256) void norm_k(const float* __restrict__ w,
                                              float* __restrict__ nT) {
    const int k = blockIdx.x;
    const int lane = threadIdx.x & 63;
    const int wave = threadIdx.x >> 6;
    float mn = 1e30f, mx = -1e30f;
    for (int d = threadIdx.x; d < D_DIM; d += 256) {
        float v = w[d * K_DIM + k];
        mn = fminf(mn, v);
        mx = fmaxf(mx, v);
    }
#pragma unroll
    for (int off = 32; off > 0; off >>= 1) {
        mn = fminf(mn, __shfl_xor(mn, off, 64));
        mx = fmaxf(mx, __shfl_xor(mx, off, 64));
    }
    __shared__ float red[8];
    if (lane == 0) { red[wave] = mn; red[4 + wave] = mx; }
    __syncthreads();
    mn = fminf(fminf(red[0], red[1]), fminf(red[2], red[3]));
    mx = fmaxf(fmaxf(red[4], red[5]), fmaxf(red[6], red[7]));
    const float inv = 1.0f / (mx - mn);
    for (int d = threadIdx.x; d < D_DIM; d += 256) {
        nT[k * D_DIM + d] = (w[d * K_DIM + k] - mn) * inv;
    }
}

// ---------------------------------------------------------------------------
// Kernel C1: scores = X @ P (fp32 VALU) -> per-row (argmax, sign).
// v8 = v6 (32 rows, 4 waves = d-quarters, dbuf + counted vmcnt) with the
// lane remap kk=4 -> kk=8 to HALVE the LDS instruction count:
//   rg = lane>>3 (8 groups x 4 rows), kg = lane&7 (k = kg*8 .. +7).
//   acc[4][8]; per chunk: 4 ds_read_b128 (was 8) feeding 128 FMAs
//   (32 FMAs per LDS read, was 16). LDS pipe demand per CU per iter:
//   12.3K cy -> 6.1K cy, below the 8.2K cy VALU floor -> VALU-bound.
// Swizzle re-derived: read slot = c ^ rg (rg 0..7 -> 8 distinct 16B slots
// = all 32 banks once, conflict-free); staging slot = lane&15, src
// d-offset = ((lane&15) ^ j) << 2 (rows j*4..j*4+3 have rg == j).
// Per-(row,k) fmaf chain over d UNCHANGED -> stats bit-identical.
// ---------------------------------------------------------------------------
__global__ __launch_bounds__(256, 2) void gemm_stats_k(const float* __restrict__ x,
                                                       const float* __restrict__ pC,
                                                       int* __restrict__ stats) {
    const int lane = threadIdx.x & 63;
    const int wave = threadIdx.x >> 6;
    const int r0 = blockIdx.x * 32;
    const int dw0 = wave * (D_DIM / 4);            // this wave's d-quarter
    const int rg = lane >> 3;                      // 0..7: rows rg*4..rg*4+3
    const int kg = lane & 7;                       // k = kg*8 + kk

    __shared__ float xs_all[4][2][32 * 64];        // 64 KB: per-wave double buffer
    float* cur = &xs_all[wave][0][0];
    float* nxt = &xs_all[wave][1][0];

    float acc[4][8];
#pragma unroll
    for (int rr = 0; rr < 4; ++rr)
#pragma unroll
        for (int kk = 0; kk < 8; ++kk) acc[rr][kk] = 0.0f;

    const float* __restrict__ xg = x + (size_t)r0 * D_DIM + dw0;   // wave x panel
    // packed pC: lane's 8 k rows start at k = kg*8 -> offset kg*32 floats
    const float* __restrict__ pgBase = pC + (size_t)(wave * 128) * 256 + kg * 32;

    const int srow = lane >> 4;                    // staging row within group of 4
    const int slот_dummy = 0; (void)slот_dummy;
    const int sslot = lane & 15;                   // staging slot 0..15

    // ---- prologue: stage tile 0 into cur (8 x 1KB; instr j covers rows j*4..+3)
#pragma unroll
    for (int j = 0; j < 8; ++j) {
        const float* src = xg + (size_t)(j * 4 + srow) * D_DIM + ((sslot ^ j) << 2);
        __builtin_amdgcn_global_load_lds((glob_u32*)src, (lds_u32*)(cur + j * 256),
                                         16, 0, 0);
    }

#pragma unroll 1
    for (int it = 0; it < 8; ++it) {
        // ---- issue staging of tile it+1 into nxt, then wait ONLY for tile it
        if (it < 7) {
#pragma unroll
            for (int j = 0; j < 8; ++j) {
                const float* src = xg + (size_t)(j * 4 + srow) * D_DIM
                                   + (it + 1) * 64 + ((sslot ^ j) << 2);
                __builtin_amdgcn_global_load_lds((glob_u32*)src,
                                                 (lds_u32*)(nxt + j * 256),
                                                 16, 0, 0);
            }
            asm volatile("s_waitcnt vmcnt(8)" ::: "memory");
        } else {
            asm volatile("s_waitcnt vmcnt(0)" ::: "memory");
        }

        // ---- compute: 16 sub-chunks of 4 d; 4 LDS reads + 128 FMAs each
#pragma unroll
        for (int c = 0; c < 16; ++c) {
            const float* pcc = pgBase + (size_t)(it * 16 + c) * 256;
            float4 pv[8];
#pragma unroll
            for (int kk = 0; kk < 8; ++kk)
                pv[kk] = *(const float4*)(pcc + kk * 4);
#pragma unroll
            for (int rr = 0; rr < 4; ++rr) {
                const int row = rg * 4 + rr;
                const float4 xv = *(const float4*)(cur + row * 64 + ((c ^ rg) << 2));
#pragma unroll
                for (int kk = 0; kk < 8; ++kk) {
                    float a = acc[rr][kk];
                    a = fmaf(xv.x, pv[kk].x, a);
                    a = fmaf(xv.y, pv[kk].y, a);
                    a = fmaf(xv.z, pv[kk].z, a);
                    a = fmaf(xv.w, pv[kk].w, a);
                    acc[rr][kk] = a;
                }
            }
        }
        float* t = cur; cur = nxt; nxt = t;
    }

    // ---- cross-wave reduction + 64-lane argmax (same values, same order) --
    __syncthreads();                               // all waves done with xs
    float (*red)[32][64] = reinterpret_cast<float (*)[32][64]>(&xs_all[0][0][0]);
#pragma unroll
    for (int rr = 0; rr < 4; ++rr)
#pragma unroll
        for (int kk = 0; kk < 8; ++kk)
            red[wave][rg * 4 + rr][kg * 8 + kk] = acc[rr][kk];
    __syncthreads();

#pragma unroll
    for (int rr = 0; rr < 8; ++rr) {
        const int r = wave * 8 + rr;
        float v = red[0][r][lane] + red[1][r][lane] + red[2][r][lane] + red[3][r][lane];
        int idx = lane;
#pragma unroll
        for (int off = 32; off > 0; off >>= 1) {
            const float ov = __shfl_xor(v, off, 64);
            const int oi = __shfl_xor(idx, off, 64);
            if (ov > v || (ov == v && oi < idx)) { v = ov; idx = oi; }
        }
        if (lane == 0) stats[r0 + r] = idx | ((v < 0.0f) ? (1 << 8) : 0);
    }
}

// ---------------------------------------------------------------------------
// Kernel C2: out[r,d] = x[r,d] * (1 + W), W from stats[r-1]; rows t==0: W=0.
// 1 row per block (grid 16384) - measured at the 41us BW floor in R0/R1.
// ---------------------------------------------------------------------------
__global__ __launch_bounds__(256) void output_k(const float* __restrict__ x,
                                                const float* __restrict__ nT,
                                                const int* __restrict__ stats,
                                                float* __restrict__ out) {
    const int row = blockIdx.x;
    const int t = row & (T_DIM - 1);
    const float4* x4 = (const float4*)(x + (size_t)row * D_DIM);
    float4* o4 = (float4*)(out + (size_t)row * D_DIM);
    if (t == 0) {
#pragma unroll
        for (int it = 0; it < 2; ++it) {
            const int i = threadIdx.x + it * 256;
            o4[i] = x4[i];
        }
        return;
    }
    const int s = stats[row - 1];
    const int ind = s & 0xff;
    const bool neg = (s >> 8) & 1;
    const float4* n4 = (const float4*)(nT + (size_t)ind * D_DIM);
#pragma unroll
    for (int it = 0; it < 2; ++it) {
        const int i = threadIdx.x + it * 256;
        const float4 xv = x4[i];
        const float4 nv = n4[i];
        float4 r;
        const float w0 = neg ? 1.0f - nv.x : nv.x;
        const float w1 = neg ? 1.0f - nv.y : nv.y;
        const float w2 = neg ? 1.0f - nv.z : nv.z;
        const float w3 = neg ? 1.0f - nv.w : nv.w;
        r.x = fmaf(xv.x, w0, xv.x);
        r.y = fmaf(xv.y, w1, xv.y);
        r.z = fmaf(xv.z, w2, xv.z);
        r.w = fmaf(xv.w, w3, xv.w);
        o4[i] = r;
    }
}

extern "C" void kernel_launch(void* const* d_in, const int* in_sizes, int n_in,
                              void* d_out, int out_size, void* d_ws, size_t ws_size,
                              hipStream_t stream) {
    const float* x = (const float*)d_in[0];   // [B,T,D] fp32
    const float* w = (const float*)d_in[1];   // [D,K] fp32
    float* out = (float*)d_out;

    float* pC = (float*)d_ws;                 // [D/4][K][4] packed softmax, 512 KB
    float* nT = pC + (size_t)K_DIM * D_DIM;   // [K,D]  512 KB
    int* stats = (int*)(nT + (size_t)K_DIM * D_DIM);  // [B*T] 64 KB

    softmax_k<<<D_DIM / 4, 256, 0, stream>>>(w, pC);
    norm_k<<<K_DIM, 256, 0, stream>>>(w, nT);
    gemm_stats_k<<<BT_DIM / 32, 256, 0, stream>>>(x, pC, stats);
    output_k<<<BT_DIM, 256, 0, stream>>>(x, nT, stats, out);
}

// Round 9
// 313.415 us; speedup vs baseline: 1.4459x; 1.4459x over previous
//
#include <hip/hip_runtime.h>
#include <stdint.h>

#define D_DIM 2048
#define K_DIM 64
#define T_DIM 2048
#define BT_DIM 16384   // B*T = 8*2048

typedef __attribute__((address_space(3))) uint32_t lds_u32;
typedef const __attribute__((address_space(1))) uint32_t glob_u32;

// ---------------------------------------------------------------------------
// Kernel A: softmax over k of w[d,:], stored PACKED+INTERLEAVED for the gemm:
//   pC8[(d>>2)*256 + (k&7)*32 + (k>>3)*4 + (d&3)] = softmax(w[d,:])[k]
// With gemm lanes kg = lane&7 owning k = kg*8..+7, the pv load for fixed kk
// reads addresses kg*16B, kg=0..7 -> ONE contiguous 128B segment per
// instruction (v8's [d/4][k][4] layout made it 8 segments -> TA-bound).
// ---------------------------------------------------------------------------
__global__ __launch_bounds__(256) void softmax_k(const float* __restrict__ w,
                                                 float* __restrict__ pC) {
    const int lane = threadIdx.x & 63;
    const int d = blockIdx.x * 4 + (threadIdx.x >> 6);
    float v = w[d * K_DIM + lane];
    float m = v;
#pragma unroll
    for (int off = 32; off > 0; off >>= 1) m = fmaxf(m, __shfl_xor(m, off, 64));
    float e = expf(v - m);
    float s = e;
#pragma unroll
    for (int off = 32; off > 0; off >>= 1) s += __shfl_xor(s, off, 64);
    pC[(d >> 2) * 256 + (lane & 7) * 32 + (lane >> 3) * 4 + (d & 3)] = e / s;
}

// ---------------------------------------------------------------------------
// Kernel B: per-column min/max of w -> nT[k,d] = (w[d,k]-mn)/(mx-mn).
// ---------------------------------------------------------------------------
__global__ __launch_bounds__(256) void norm_k(const float* __restrict__ w,
                                              float* __restrict__ nT) {
    const int k = blockIdx.x;
    const int lane = threadIdx.x & 63;
    const int wave = threadIdx.x >> 6;
    float mn = 1e30f, mx = -1e30f;
    for (int d = threadIdx.x; d < D_DIM; d += 256) {
        float v = w[d * K_DIM + k];
        mn = fminf(mn, v);
        mx = fmaxf(mx, v);
    }
#pragma unroll
    for (int off = 32; off > 0; off >>= 1) {
        mn = fminf(mn, __shfl_xor(mn, off, 64));
        mx = fmaxf(mx, __shfl_xor(mx, off, 64));
    }
    __shared__ float red[8];
    if (lane == 0) { red[wave] = mn; red[4 + wave] = mx; }
    __syncthreads();
    mn = fminf(fminf(red[0], red[1]), fminf(red[2], red[3]));
    mx = fmaxf(fmaxf(red[4], red[5]), fmaxf(red[6], red[7]));
    const float inv = 1.0f / (mx - mn);
    for (int d = threadIdx.x; d < D_DIM; d += 256) {
        nT[k * D_DIM + d] = (w[d * K_DIM + k] - mn) * inv;
    }
}

// ---------------------------------------------------------------------------
// Kernel C1: scores = X @ P (fp32 VALU) -> per-row (argmax, sign).
// v9 = v8 (kk=8 remap: rg=lane>>3 owns 4 rows, kg=lane&7 owns 8 k's;
//          4 ds_read_b128 + 128 FMAs per chunk; dbuf + counted vmcnt)
// with the two v8 pathologies fixed:
//  1. pv loads read the INTERLEAVED pC8 layout -> each of the 8 loads per
//     chunk is one contiguous 128B wave-segment (TA ~1K cy/CU/iter, was 8K+).
//  2. Reduction store swizzled: red[w][row][(k + (row>>2)) & 63] -> write
//     banks (8kg+rg+kk)%32 cover all 32 banks 2-way (free, was 8-way);
//     read uses the same shift (2-way, free).
// Pipe budget/CU/iter: LDS 6.1K cy, TA ~1K cy, VALU 8.2K cy -> VALU-bound.
// Per-(row,k) fmaf chain over d UNCHANGED -> stats bit-identical.
// ---------------------------------------------------------------------------
__global__ __launch_bounds__(256, 2) void gemm_stats_k(const float* __restrict__ x,
                                                       const float* __restrict__ pC,
                                                       int* __restrict__ stats) {
    const int lane = threadIdx.x & 63;
    const int wave = threadIdx.x >> 6;
    const int r0 = blockIdx.x * 32;
    const int dw0 = wave * (D_DIM / 4);            // this wave's d-quarter
    const int rg = lane >> 3;                      // 0..7: rows rg*4..rg*4+3
    const int kg = lane & 7;                       // k = kg*8 + kk

    __shared__ float xs_all[4][2][32 * 64];        // 64 KB: per-wave double buffer
    float* cur = &xs_all[wave][0][0];
    float* nxt = &xs_all[wave][1][0];

    float acc[4][8];
#pragma unroll
    for (int rr = 0; rr < 4; ++rr)
#pragma unroll
        for (int kk = 0; kk < 8; ++kk) acc[rr][kk] = 0.0f;

    const float* __restrict__ xg = x + (size_t)r0 * D_DIM + dw0;   // wave x panel
    // interleaved pC8: lane's slice starts at kg*4 floats within each chunk
    const float* __restrict__ pgBase = pC + (size_t)(wave * 128) * 256 + kg * 4;

    const int srow = lane >> 4;                    // staging row within group of 4
    const int sslot = lane & 15;                   // staging slot 0..15

    // ---- prologue: stage tile 0 into cur (8 x 1KB; instr j covers rows j*4..+3)
#pragma unroll
    for (int j = 0; j < 8; ++j) {
        const float* src = xg + (size_t)(j * 4 + srow) * D_DIM + ((sslot ^ j) << 2);
        __builtin_amdgcn_global_load_lds((glob_u32*)src, (lds_u32*)(cur + j * 256),
                                         16, 0, 0);
    }

#pragma unroll 1
    for (int it = 0; it < 8; ++it) {
        // ---- issue staging of tile it+1 into nxt, then wait ONLY for tile it
        if (it < 7) {
#pragma unroll
            for (int j = 0; j < 8; ++j) {
                const float* src = xg + (size_t)(j * 4 + srow) * D_DIM
                                   + (it + 1) * 64 + ((sslot ^ j) << 2);
                __builtin_amdgcn_global_load_lds((glob_u32*)src,
                                                 (lds_u32*)(nxt + j * 256),
                                                 16, 0, 0);
            }
            asm volatile("s_waitcnt vmcnt(8)" ::: "memory");
        } else {
            asm volatile("s_waitcnt vmcnt(0)" ::: "memory");
        }

        // ---- compute: 16 sub-chunks of 4 d; 4 LDS reads + 8 pv loads + 128 FMAs
#pragma unroll
        for (int c = 0; c < 16; ++c) {
            const float* pcc = pgBase + (size_t)(it * 16 + c) * 256;
            float4 pv[8];
#pragma unroll
            for (int kk = 0; kk < 8; ++kk)
                pv[kk] = *(const float4*)(pcc + kk * 32);
#pragma unroll
            for (int rr = 0; rr < 4; ++rr) {
                const int row = rg * 4 + rr;
                const float4 xv = *(const float4*)(cur + row * 64 + ((c ^ rg) << 2));
#pragma unroll
                for (int kk = 0; kk < 8; ++kk) {
                    float a = acc[rr][kk];
                    a = fmaf(xv.x, pv[kk].x, a);
                    a = fmaf(xv.y, pv[kk].y, a);
                    a = fmaf(xv.z, pv[kk].z, a);
                    a = fmaf(xv.w, pv[kk].w, a);
                    acc[rr][kk] = a;
                }
            }
        }
        float* t = cur; cur = nxt; nxt = t;
    }

    // ---- cross-wave reduction + 64-lane argmax --------------------------
    // Store col swizzled by (row>>2) so b32 writes are 2-way (free):
    //   red[w][row][(k + (row>>2)) & 63]; read applies the same shift.
    __syncthreads();                               // all waves done with xs
    float (*red)[32][64] = reinterpret_cast<float (*)[32][64]>(&xs_all[0][0][0]);
#pragma unroll
    for (int rr = 0; rr < 4; ++rr) {
        const int row = rg * 4 + rr;
#pragma unroll
        for (int kk = 0; kk < 8; ++kk)
            red[wave][row][(kg * 8 + kk + rg) & 63] = acc[rr][kk];
    }
    __syncthreads();

#pragma unroll
    for (int rr = 0; rr < 8; ++rr) {
        const int r = wave * 8 + rr;
        const int cl = (lane + (r >> 2)) & 63;
        float v = red[0][r][cl] + red[1][r][cl] + red[2][r][cl] + red[3][r][cl];
        int idx = lane;
#pragma unroll
        for (int off = 32; off > 0; off >>= 1) {
            const float ov = __shfl_xor(v, off, 64);
            const int oi = __shfl_xor(idx, off, 64);
            if (ov > v || (ov == v && oi < idx)) { v = ov; idx = oi; }
        }
        if (lane == 0) stats[r0 + r] = idx | ((v < 0.0f) ? (1 << 8) : 0);
    }
}

// ---------------------------------------------------------------------------
// Kernel C2: out[r,d] = x[r,d] * (1 + W), W from stats[r-1]; rows t==0: W=0.
// 1 row per block (grid 16384) - measured at the 41us BW floor in R0/R1.
// ---------------------------------------------------------------------------
__global__ __launch_bounds__(256) void output_k(const float* __restrict__ x,
                                                const float* __restrict__ nT,
                                                const int* __restrict__ stats,
                                                float* __restrict__ out) {
    const int row = blockIdx.x;
    const int t = row & (T_DIM - 1);
    const float4* x4 = (const float4*)(x + (size_t)row * D_DIM);
    float4* o4 = (float4*)(out + (size_t)row * D_DIM);
    if (t == 0) {
#pragma unroll
        for (int it = 0; it < 2; ++it) {
            const int i = threadIdx.x + it * 256;
            o4[i] = x4[i];
        }
        return;
    }
    const int s = stats[row - 1];
    const int ind = s & 0xff;
    const bool neg = (s >> 8) & 1;
    const float4* n4 = (const float4*)(nT + (size_t)ind * D_DIM);
#pragma unroll
    for (int it = 0; it < 2; ++it) {
        const int i = threadIdx.x + it * 256;
        const float4 xv = x4[i];
        const float4 nv = n4[i];
        float4 r;
        const float w0 = neg ? 1.0f - nv.x : nv.x;
        const float w1 = neg ? 1.0f - nv.y : nv.y;
        const float w2 = neg ? 1.0f - nv.z : nv.z;
        const float w3 = neg ? 1.0f - nv.w : nv.w;
        r.x = fmaf(xv.x, w0, xv.x);
        r.y = fmaf(xv.y, w1, xv.y);
        r.z = fmaf(xv.z, w2, xv.z);
        r.w = fmaf(xv.w, w3, xv.w);
        o4[i] = r;
    }
}

extern "C" void kernel_launch(void* const* d_in, const int* in_sizes, int n_in,
                              void* d_out, int out_size, void* d_ws, size_t ws_size,
                              hipStream_t stream) {
    const float* x = (const float*)d_in[0];   // [B,T,D] fp32
    const float* w = (const float*)d_in[1];   // [D,K] fp32
    float* out = (float*)d_out;

    float* pC = (float*)d_ws;                 // [D/4][k&7][k>>3][d&3] packed, 512 KB
    float* nT = pC + (size_t)K_DIM * D_DIM;   // [K,D]  512 KB
    int* stats = (int*)(nT + (size_t)K_DIM * D_DIM);  // [B*T] 64 KB

    softmax_k<<<D_DIM / 4, 256, 0, stream>>>(w, pC);
    norm_k<<<K_DIM, 256, 0, stream>>>(w, nT);
    gemm_stats_k<<<BT_DIM / 32, 256, 0, stream>>>(x, pC, stats);
    output_k<<<BT_DIM, 256, 0, stream>>>(x, nT, stats, out);
}